// Round 1
// baseline (2108.283 us; speedup 1.0000x reference)
//
#include <hip/hip_runtime.h>
#include <math.h>

#define NNODES 65536
#define KNBR 27
#define EPS_BN 1e-5f
#define LOG_P 4.6151205168412597f

// ---------------- stage 1: entropy gate + rgb/img matvec -> x64 ----------------
__global__ __launch_bounds__(256) void stage1_kernel(
    const float* __restrict__ feats,
    const float* __restrict__ w_rgb, const float* __restrict__ b_rgb, const float* __restrict__ bn_rgb,
    const float* __restrict__ w_img, const float* __restrict__ b_img, const float* __restrict__ bn_img,
    float* __restrict__ x64)
{
    __shared__ float s_f[4][106];
    const int wid  = threadIdx.x >> 6;
    const int lane = threadIdx.x & 63;
    const int n = blockIdx.x * 4 + wid;
    const float* fr = feats + (size_t)n * 105;
    for (int i = lane; i < 105; i += 64) s_f[wid][i] = fr[i];
    __syncthreads();

    float s = 0.f;
    for (int i = lane; i < 101; i += 64) {
        float pv = s_f[wid][4 + i];
        float ps = fmaxf(pv, 1e-12f);
        s += ps * logf(ps);
    }
    #pragma unroll
    for (int off = 32; off > 0; off >>= 1) s += __shfl_xor(s, off, 64);
    const float wgt = 1.0f + s * (1.0f / LOG_P);   // 1 - H/LOG_P, H = -s

    if (lane < 32) {
        const int j = lane;
        float acc = b_rgb[j];
        #pragma unroll
        for (int c = 0; c < 4; ++c) acc += s_f[wid][c] * w_rgb[c*32 + j];
        float y = bn_rgb[j] * (acc - bn_rgb[64+j]) * rsqrtf(bn_rgb[96+j] + EPS_BN) + bn_rgb[32+j];
        x64[(size_t)n*64 + j] = fmaxf(y, 0.f);
    } else {
        const int j = lane - 32;
        float acc = 0.f;
        for (int c = 0; c < 101; ++c) acc += s_f[wid][4+c] * w_img[c*32 + j];
        acc = acc * wgt + b_img[j];
        float y = bn_img[j] * (acc - bn_img[64+j]) * rsqrtf(bn_img[96+j] + EPS_BN) + bn_img[32+j];
        x64[(size_t)n*64 + 32 + j] = fmaxf(y, 0.f);
    }
}

// ---------------- spconv: out[n,d] = relu(bn(sum_k sum_c x[nbr[n,k],c] * W[k,c,d])) ----------------
template<int CIN>
__global__ __launch_bounds__(256) void spconv_kernel(
    const float* __restrict__ xin, const int* __restrict__ nbr,
    const float* __restrict__ W, const float* __restrict__ bnp,
    float* __restrict__ xout)
{
    constexpr int TN   = 64;
    constexpr int HALF = CIN / 2;
    constexpr int PAD  = CIN + 2;          // even pad: float2-aligned rows, conflict-free node stride
    __shared__ int s_nbr[TN * KNBR];
    __shared__ __align__(16) float s_g[TN][PAD];
    __shared__ __align__(16) float s_w[HALF * 96];

    const int t  = threadIdx.x;
    const int n0 = blockIdx.x * TN;

    for (int i = t; i < TN * KNBR; i += 256) s_nbr[i] = nbr[(size_t)n0 * KNBR + i];

    const int td = t & 15;                 // 16 d-groups of 6
    const int tn = t >> 4;                 // 16 node-groups of 4
    const int d0 = td * 6;
    const int r0 = tn * 4;

    float acc[4][6];
    #pragma unroll
    for (int i = 0; i < 4; ++i)
        #pragma unroll
        for (int j = 0; j < 6; ++j) acc[i][j] = 0.f;

    for (int k = 0; k < KNBR; ++k) {
        __syncthreads();                   // previous compute done reading s_g
        for (int i = t; i < TN * (CIN/4); i += 256) {
            const int r = i / (CIN/4);
            const int q = i - r * (CIN/4);
            const int nb = s_nbr[r * KNBR + k];
            const float4 v = *(const float4*)(xin + (size_t)nb * CIN + q * 4);
            s_g[r][q*4+0] = v.x; s_g[r][q*4+1] = v.y;
            s_g[r][q*4+2] = v.z; s_g[r][q*4+3] = v.w;
        }
        #pragma unroll
        for (int h = 0; h < 2; ++h) {
            __syncthreads();               // prev compute done with s_w; gather visible (h==0)
            {
                const float4* wsrc = (const float4*)(W + ((size_t)k * CIN + (size_t)h * HALF) * 96);
                float4* wdst = (float4*)s_w;
                for (int i = t; i < HALF * 24; i += 256) wdst[i] = wsrc[i];
            }
            __syncthreads();
            const int hc = h * HALF;
            for (int c = 0; c < HALF; c += 2) {
                const float2 ga0 = *(const float2*)&s_g[r0+0][hc + c];
                const float2 ga1 = *(const float2*)&s_g[r0+1][hc + c];
                const float2 ga2 = *(const float2*)&s_g[r0+2][hc + c];
                const float2 ga3 = *(const float2*)&s_g[r0+3][hc + c];
                const float* wr0 = s_w + c * 96 + d0;
                const float* wr1 = wr0 + 96;
                const float2 wa0 = *(const float2*)&wr0[0];
                const float2 wa1 = *(const float2*)&wr0[2];
                const float2 wa2 = *(const float2*)&wr0[4];
                const float2 wb0 = *(const float2*)&wr1[0];
                const float2 wb1 = *(const float2*)&wr1[2];
                const float2 wb2 = *(const float2*)&wr1[4];
                const float wc0[6] = {wa0.x, wa0.y, wa1.x, wa1.y, wa2.x, wa2.y};
                const float wc1[6] = {wb0.x, wb0.y, wb1.x, wb1.y, wb2.x, wb2.y};
                #pragma unroll
                for (int j = 0; j < 6; ++j) {
                    acc[0][j] += ga0.x*wc0[j] + ga0.y*wc1[j];
                    acc[1][j] += ga1.x*wc0[j] + ga1.y*wc1[j];
                    acc[2][j] += ga2.x*wc0[j] + ga2.y*wc1[j];
                    acc[3][j] += ga3.x*wc0[j] + ga3.y*wc1[j];
                }
            }
        }
    }
    // epilogue: bn + relu
    #pragma unroll
    for (int j = 0; j < 6; ++j) {
        const int d = d0 + j;
        const float sc = bnp[d] * rsqrtf(bnp[288 + d] + EPS_BN);
        const float mb = bnp[192 + d];
        const float bb = bnp[96 + d];
        #pragma unroll
        for (int i = 0; i < 4; ++i) {
            const float y = sc * (acc[i][j] - mb) + bb;
            xout[(size_t)(n0 + r0 + i) * 96 + d] = fmaxf(y, 0.f);
        }
    }
}

// ---------------- heads: lab / unlab / over ----------------
__global__ __launch_bounds__(256) void heads_kernel(
    const float* __restrict__ x,
    const float* __restrict__ w_lab, const float* __restrict__ w_unlab, const float* __restrict__ w_over,
    float* __restrict__ out_lab, float* __restrict__ out_unlab, float* __restrict__ out_over)
{
    constexpr int TN = 32;
    constexpr int DH = 119;                // 19 + 25 + 75
    __shared__ float s_x[TN][96];
    __shared__ float s_w[96 * DH];
    const int t  = threadIdx.x;
    const int n0 = blockIdx.x * TN;
    for (int i = t; i < TN*96; i += 256) s_x[i/96][i%96] = x[(size_t)n0*96 + i];
    for (int i = t; i < 96*19; i += 256)  { int c=i/19,  j=i-c*19;                      s_w[c*DH + j] = w_lab[i]; }
    for (int i = t; i < 5*96*5; i += 256) { int h=i/480, rm=i-h*480, c=rm/5,  p=rm-c*5;  s_w[c*DH + 19 + h*5  + p] = w_unlab[i]; }
    for (int i = t; i < 5*96*15; i += 256){ int h=i/1440,rm=i-h*1440,c=rm/15, p=rm-c*15; s_w[c*DH + 44 + h*15 + p] = w_over[i]; }
    __syncthreads();
    for (int o = t; o < TN*DH; o += 256) {
        const int r = o / DH, j = o - r*DH;
        float acc = 0.f;
        for (int c = 0; c < 96; ++c) acc += s_x[r][c] * s_w[c*DH + j];
        const int n = n0 + r;
        if (j < 19)      out_lab[(size_t)n*19 + j] = acc;
        else if (j < 44) { int jj=j-19, h=jj/5,  p=jj-h*5;  out_unlab[((size_t)h*NNODES + n)*5  + p] = acc; }
        else             { int jj=j-44, h=jj/15, p=jj-h*15; out_over [((size_t)h*NNODES + n)*15 + p] = acc; }
    }
}

// ---------------- clip: h = relu(bn(x@w1+b1)); out = h@w2+b2 ----------------
__global__ __launch_bounds__(256) void clip_kernel(
    const float* __restrict__ x,
    const float* __restrict__ w1, const float* __restrict__ b1, const float* __restrict__ bnp,
    const float* __restrict__ w2, const float* __restrict__ b2,
    float* __restrict__ outc)
{
    constexpr int TN = 16;
    __shared__ __align__(16) float s_x[TN][96];
    __shared__ __align__(16) float s_h[TN][258];
    const int t  = threadIdx.x;
    const int n0 = blockIdx.x * TN;
    for (int i = t; i < TN*96; i += 256) s_x[i/96][i%96] = x[(size_t)n0*96 + i];
    __syncthreads();
    {   // phase 1: column t of h for all TN rows
        float acc[TN];
        #pragma unroll
        for (int r = 0; r < TN; ++r) acc[r] = 0.f;
        for (int c = 0; c < 96; c += 2) {
            const float wv0 = w1[c*256 + t];
            const float wv1 = w1[(c+1)*256 + t];
            #pragma unroll
            for (int r = 0; r < TN; ++r) {
                const float2 xv = *(const float2*)&s_x[r][c];
                acc[r] += xv.x*wv0 + xv.y*wv1;
            }
        }
        const float sc = bnp[t] * rsqrtf(bnp[768 + t] + EPS_BN);
        const float mb = bnp[512 + t];
        const float bb = bnp[256 + t];
        const float bias = b1[t];
        #pragma unroll
        for (int r = 0; r < TN; ++r)
            s_h[r][t] = fmaxf(sc * (acc[r] + bias - mb) + bb, 0.f);
    }
    __syncthreads();
    {   // phase 2: columns t and t+256 of clip for all TN rows
        float acc0[TN], acc1[TN];
        #pragma unroll
        for (int r = 0; r < TN; ++r) { acc0[r] = 0.f; acc1[r] = 0.f; }
        for (int c = 0; c < 256; c += 2) {
            const float w00 = w2[(size_t)c*512 + t];
            const float w01 = w2[(size_t)c*512 + 256 + t];
            const float w10 = w2[(size_t)(c+1)*512 + t];
            const float w11 = w2[(size_t)(c+1)*512 + 256 + t];
            #pragma unroll
            for (int r = 0; r < TN; ++r) {
                const float2 hv = *(const float2*)&s_h[r][c];
                acc0[r] += hv.x*w00 + hv.y*w10;
                acc1[r] += hv.x*w01 + hv.y*w11;
            }
        }
        const float bb0 = b2[t], bb1 = b2[256 + t];
        #pragma unroll
        for (int r = 0; r < TN; ++r) {
            outc[(size_t)(n0 + r)*512 + t]       = acc0[r] + bb0;
            outc[(size_t)(n0 + r)*512 + 256 + t] = acc1[r] + bb1;
        }
    }
}

extern "C" void kernel_launch(void* const* d_in, const int* in_sizes, int n_in,
                              void* d_out, int out_size, void* d_ws, size_t ws_size,
                              hipStream_t stream)
{
    const float* feats   = (const float*)d_in[0];
    const int*   nbr1    = (const int*)  d_in[1];
    const int*   nbr2    = (const int*)  d_in[2];
    const float* w_rgb   = (const float*)d_in[3];
    const float* b_rgb   = (const float*)d_in[4];
    const float* bn_rgb  = (const float*)d_in[5];
    const float* w_img   = (const float*)d_in[6];
    const float* b_img   = (const float*)d_in[7];
    const float* bn_img  = (const float*)d_in[8];
    const float* w_e1    = (const float*)d_in[9];
    const float* w_e2    = (const float*)d_in[10];
    const float* bn_e1   = (const float*)d_in[11];
    const float* bn_e2   = (const float*)d_in[12];
    const float* w_lab   = (const float*)d_in[13];
    const float* w_unlab = (const float*)d_in[14];
    const float* w_over  = (const float*)d_in[15];
    const float* w_clip1 = (const float*)d_in[16];
    const float* b_clip1 = (const float*)d_in[17];
    const float* bn_clip = (const float*)d_in[18];
    const float* w_clip2 = (const float*)d_in[19];
    const float* b_clip2 = (const float*)d_in[20];

    float* out = (float*)d_out;
    const size_t off_unlab = (size_t)NNODES * 19;
    const size_t off_over  = (size_t)NNODES * 44;
    const size_t off_x     = (size_t)NNODES * 119;
    const size_t off_clip  = (size_t)NNODES * 215;

    // scratch lives inside the clip-feats output region (dead before clip_kernel writes it)
    float* x64  = out + off_clip;
    float* x96a = out + off_clip + (size_t)NNODES * 64;

    stage1_kernel<<<NNODES/4, 256, 0, stream>>>(feats, w_rgb, b_rgb, bn_rgb, w_img, b_img, bn_img, x64);
    spconv_kernel<64><<<NNODES/64, 256, 0, stream>>>(x64,  nbr1, w_e1, bn_e1, x96a);
    spconv_kernel<96><<<NNODES/64, 256, 0, stream>>>(x96a, nbr2, w_e2, bn_e2, out + off_x);
    heads_kernel<<<NNODES/32, 256, 0, stream>>>(out + off_x, w_lab, w_unlab, w_over,
                                                out, out + off_unlab, out + off_over);
    clip_kernel<<<NNODES/16, 256, 0, stream>>>(out + off_x, w_clip1, b_clip1, bn_clip,
                                               w_clip2, b_clip2, out + off_clip);
}

// Round 2
// 707.195 us; speedup vs baseline: 2.9812x; 2.9812x over previous
//
#include <hip/hip_runtime.h>
#include <math.h>

#define NNODES 65536
#define KNBR 27
#define EPS_BN 1e-5f
#define LOG_P 4.6151205168412597f

typedef float f32x4 __attribute__((ext_vector_type(4)));
typedef short s16x8 __attribute__((ext_vector_type(8)));   // 8 bf16 in 4 VGPRs

__device__ __forceinline__ unsigned short f2bf(float f) {
    union { float f; unsigned int u; } v; v.f = f;
    unsigned int u = v.u;
    unsigned int r = (u + 0x7fffu + ((u >> 16) & 1u)) >> 16;   // RNE
    return (unsigned short)r;
}

__device__ __forceinline__ void gload16(const void* g, void* l) {
    __builtin_amdgcn_global_load_lds(
        (const __attribute__((address_space(1))) void*)g,
        (__attribute__((address_space(3))) void*)l, 16, 0, 0);
}

// ---------------- W preprocessing: [k][cin][dout] f32 -> [k][dout][chunk swizzled] bf16 ----------------
// wpre[((k*96 + r)*NCH + ci)*8 + e] = bf16( W[k][cin][r] ), cin = (ci ^ (r & (NCH-1)))*8 + e, 0 if cin >= CIN
__global__ __launch_bounds__(256) void prep_w_kernel(
    const float* __restrict__ W, unsigned short* __restrict__ wpre, int CIN, int NCH)
{
    const int idx = blockIdx.x * 256 + threadIdx.x;
    const int total = KNBR * 96 * NCH * 8;
    if (idx >= total) return;
    const int e  = idx & 7;
    const int t1 = idx >> 3;
    const int ci = t1 % NCH;
    const int t2 = t1 / NCH;
    const int r  = t2 % 96;
    const int k  = t2 / 96;
    const int cc  = ci ^ (r & (NCH - 1));
    const int cin = cc * 8 + e;
    float v = (cin < CIN) ? W[((size_t)k * CIN + cin) * 96 + r] : 0.f;
    wpre[idx] = f2bf(v);
}

// ---------------- stage 1: entropy gate + rgb/img matvec -> x64 (bf16) ----------------
__global__ __launch_bounds__(256) void stage1_kernel(
    const float* __restrict__ feats,
    const float* __restrict__ w_rgb, const float* __restrict__ b_rgb, const float* __restrict__ bn_rgb,
    const float* __restrict__ w_img, const float* __restrict__ b_img, const float* __restrict__ bn_img,
    unsigned short* __restrict__ x64b)
{
    __shared__ float s_f[4][106];
    const int wid  = threadIdx.x >> 6;
    const int lane = threadIdx.x & 63;
    const int n = blockIdx.x * 4 + wid;
    const float* fr = feats + (size_t)n * 105;
    for (int i = lane; i < 105; i += 64) s_f[wid][i] = fr[i];
    __syncthreads();

    float s = 0.f;
    for (int i = lane; i < 101; i += 64) {
        float pv = s_f[wid][4 + i];
        float ps = fmaxf(pv, 1e-12f);
        s += ps * logf(ps);
    }
    #pragma unroll
    for (int off = 32; off > 0; off >>= 1) s += __shfl_xor(s, off, 64);
    const float wgt = 1.0f + s * (1.0f / LOG_P);   // 1 - H/LOG_P

    if (lane < 32) {
        const int j = lane;
        float acc = b_rgb[j];
        #pragma unroll
        for (int c = 0; c < 4; ++c) acc += s_f[wid][c] * w_rgb[c*32 + j];
        float y = bn_rgb[j] * (acc - bn_rgb[64+j]) * rsqrtf(bn_rgb[96+j] + EPS_BN) + bn_rgb[32+j];
        x64b[(size_t)n*64 + j] = f2bf(fmaxf(y, 0.f));
    } else {
        const int j = lane - 32;
        float acc = 0.f;
        for (int c = 0; c < 101; ++c) acc += s_f[wid][4+c] * w_img[c*32 + j];
        acc = acc * wgt + b_img[j];
        float y = bn_img[j] * (acc - bn_img[64+j]) * rsqrtf(bn_img[96+j] + EPS_BN) + bn_img[32+j];
        x64b[(size_t)n*64 + 32 + j] = f2bf(fmaxf(y, 0.f));
    }
}

// ---------------- spconv via MFMA: out[n,d] = relu(bn(sum_k sum_c x[nbr[n,k],c] * W[k,c,d])) ----------------
// block = 256 thr (4 waves), 128 nodes; wave = 2 mtiles(16 nodes) x 6 ntiles(16 dout)
template<int CIN, bool OUTBF>
__global__ __launch_bounds__(256, 2) void spconv_mfma(
    const char* __restrict__ xinb,          // bf16 rows, stride CIN*2 bytes
    const int*  __restrict__ nbr,
    const char* __restrict__ wpre,          // bf16 [27][96][ROWB] (chunk-swizzled)
    const float* __restrict__ bnp,
    float* __restrict__ outf,
    unsigned short* __restrict__ outb)
{
    constexpr int KT   = CIN / 32;
    constexpr int NCH  = (CIN == 96) ? 16 : 8;
    constexpr int CM   = NCH - 1;
    constexpr int ROWB = NCH * 16;
    constexpr int STG  = (96 * ROWB) / 4096;

    __shared__ int s_nbr[128 * KNBR];
    __shared__ __align__(16) char s_b[2][96 * ROWB];

    const int t   = threadIdx.x;
    const int wid = t >> 6;
    const int l   = t & 63;
    const int l15 = l & 15;
    const int l4  = l >> 4;
    const int n0  = blockIdx.x * 128;

    for (int i = t; i < 128 * KNBR; i += 256) s_nbr[i] = nbr[(size_t)n0 * KNBR + i];

    f32x4 acc[2][6];
    #pragma unroll
    for (int mt = 0; mt < 2; ++mt)
        #pragma unroll
        for (int nt = 0; nt < 6; ++nt) acc[mt][nt] = (f32x4){0.f, 0.f, 0.f, 0.f};

    float sc[6], mb[6], bb[6];
    #pragma unroll
    for (int nt = 0; nt < 6; ++nt) {
        const int d = nt * 16 + l15;
        sc[nt] = bnp[d] * rsqrtf(bnp[288 + d] + EPS_BN);
        mb[nt] = bnp[192 + d];
        bb[nt] = bnp[96 + d];
    }

    s16x8 aA[2][KT], aB[2][KT];

#define STAGE(kk) do {                                                         \
    const char* _src = wpre + (size_t)(kk) * (96 * ROWB);                      \
    char* _dst = &s_b[(kk) & 1][0];                                            \
    _Pragma("unroll")                                                          \
    for (int _i = 0; _i < STG; ++_i)                                           \
        gload16(_src + _i * 4096 + t * 16, _dst + _i * 4096 + (wid << 10));    \
} while (0)

#define PRE(areg, kk) do {                                                     \
    _Pragma("unroll")                                                          \
    for (int _mt = 0; _mt < 2; ++_mt) {                                        \
        const int _nb = s_nbr[(wid * 32 + _mt * 16 + l15) * KNBR + (kk)];      \
        const char* _rp = xinb + (size_t)_nb * (CIN * 2) + (l4 << 4);          \
        _Pragma("unroll")                                                      \
        for (int _kt = 0; _kt < KT; ++_kt)                                     \
            areg[_mt][_kt] = *(const s16x8*)(_rp + _kt * 64);                  \
    }                                                                          \
} while (0)

#define COMP(areg, kk) do {                                                    \
    const char* _bb = &s_b[(kk) & 1][0];                                       \
    _Pragma("unroll")                                                          \
    for (int _kt = 0; _kt < KT; ++_kt) {                                       \
        s16x8 _bf[6];                                                          \
        _Pragma("unroll")                                                      \
        for (int _nt = 0; _nt < 6; ++_nt) {                                    \
            const int _row = _nt * 16 + l15;                                   \
            const int _c   = _kt * 4 + l4;                                     \
            _bf[_nt] = *(const s16x8*)(_bb + _row * ROWB + ((_c ^ (_row & CM)) << 4)); \
        }                                                                      \
        _Pragma("unroll")                                                      \
        for (int _nt = 0; _nt < 6; ++_nt) {                                    \
            acc[0][_nt] = __builtin_amdgcn_mfma_f32_16x16x32_bf16(areg[0][_kt], _bf[_nt], acc[0][_nt], 0, 0, 0); \
            acc[1][_nt] = __builtin_amdgcn_mfma_f32_16x16x32_bf16(areg[1][_kt], _bf[_nt], acc[1][_nt], 0, 0, 0); \
        }                                                                      \
    }                                                                          \
} while (0)

    __syncthreads();                 // s_nbr ready
    PRE(aA, 0);
    STAGE(0);
    __syncthreads();                 // B0 in LDS (vmcnt drain is the prologue cost only)

    for (int k = 0; k < 26; k += 2) {
        STAGE(k + 1);
        PRE(aB, k + 1);
        COMP(aA, k);
        __syncthreads();             // prefetches issued a full COMP earlier -> drain ~free
        STAGE(k + 2);
        PRE(aA, k + 2);
        COMP(aB, k + 1);
        __syncthreads();
    }
    COMP(aA, 26);

#undef STAGE
#undef PRE
#undef COMP

    // epilogue: bn + relu; C/D layout col=lane&15, row=(lane>>4)*4+q
    #pragma unroll
    for (int mt = 0; mt < 2; ++mt)
        #pragma unroll
        for (int nt = 0; nt < 6; ++nt) {
            const int d = nt * 16 + l15;
            #pragma unroll
            for (int q = 0; q < 4; ++q) {
                const int node = n0 + wid * 32 + mt * 16 + l4 * 4 + q;
                float y = sc[nt] * (acc[mt][nt][q] - mb[nt]) + bb[nt];
                y = fmaxf(y, 0.f);
                if (OUTBF) outb[(size_t)node * 96 + d] = f2bf(y);
                else       outf[(size_t)node * 96 + d] = y;
            }
        }
}

// ---------------- heads: lab / unlab / over ----------------
__global__ __launch_bounds__(256) void heads_kernel(
    const float* __restrict__ x,
    const float* __restrict__ w_lab, const float* __restrict__ w_unlab, const float* __restrict__ w_over,
    float* __restrict__ out_lab, float* __restrict__ out_unlab, float* __restrict__ out_over)
{
    constexpr int TN = 32;
    constexpr int DH = 119;                // 19 + 25 + 75
    __shared__ float s_x[TN][96];
    __shared__ float s_w[96 * DH];
    const int t  = threadIdx.x;
    const int n0 = blockIdx.x * TN;
    for (int i = t; i < TN*96; i += 256) s_x[i/96][i%96] = x[(size_t)n0*96 + i];
    for (int i = t; i < 96*19; i += 256)  { int c=i/19,  j=i-c*19;                      s_w[c*DH + j] = w_lab[i]; }
    for (int i = t; i < 5*96*5; i += 256) { int h=i/480, rm=i-h*480, c=rm/5,  p=rm-c*5;  s_w[c*DH + 19 + h*5  + p] = w_unlab[i]; }
    for (int i = t; i < 5*96*15; i += 256){ int h=i/1440,rm=i-h*1440,c=rm/15, p=rm-c*15; s_w[c*DH + 44 + h*15 + p] = w_over[i]; }
    __syncthreads();
    for (int o = t; o < TN*DH; o += 256) {
        const int r = o / DH, j = o - r*DH;
        float acc = 0.f;
        for (int c = 0; c < 96; ++c) acc += s_x[r][c] * s_w[c*DH + j];
        const int n = n0 + r;
        if (j < 19)      out_lab[(size_t)n*19 + j] = acc;
        else if (j < 44) { int jj=j-19, h=jj/5,  p=jj-h*5;  out_unlab[((size_t)h*NNODES + n)*5  + p] = acc; }
        else             { int jj=j-44, h=jj/15, p=jj-h*15; out_over [((size_t)h*NNODES + n)*15 + p] = acc; }
    }
}

// ---------------- clip: h = relu(bn(x@w1+b1)); out = h@w2+b2 ----------------
__global__ __launch_bounds__(256) void clip_kernel(
    const float* __restrict__ x,
    const float* __restrict__ w1, const float* __restrict__ b1, const float* __restrict__ bnp,
    const float* __restrict__ w2, const float* __restrict__ b2,
    float* __restrict__ outc)
{
    constexpr int TN = 16;
    __shared__ __align__(16) float s_x[TN][96];
    __shared__ __align__(16) float s_h[TN][258];
    const int t  = threadIdx.x;
    const int n0 = blockIdx.x * TN;
    for (int i = t; i < TN*96; i += 256) s_x[i/96][i%96] = x[(size_t)n0*96 + i];
    __syncthreads();
    {
        float acc[TN];
        #pragma unroll
        for (int r = 0; r < TN; ++r) acc[r] = 0.f;
        for (int c = 0; c < 96; c += 2) {
            const float wv0 = w1[c*256 + t];
            const float wv1 = w1[(c+1)*256 + t];
            #pragma unroll
            for (int r = 0; r < TN; ++r) {
                const float2 xv = *(const float2*)&s_x[r][c];
                acc[r] += xv.x*wv0 + xv.y*wv1;
            }
        }
        const float sc = bnp[t] * rsqrtf(bnp[768 + t] + EPS_BN);
        const float mb = bnp[512 + t];
        const float bb = bnp[256 + t];
        const float bias = b1[t];
        #pragma unroll
        for (int r = 0; r < TN; ++r)
            s_h[r][t] = fmaxf(sc * (acc[r] + bias - mb) + bb, 0.f);
    }
    __syncthreads();
    {
        float acc0[TN], acc1[TN];
        #pragma unroll
        for (int r = 0; r < TN; ++r) { acc0[r] = 0.f; acc1[r] = 0.f; }
        for (int c = 0; c < 256; c += 2) {
            const float w00 = w2[(size_t)c*512 + t];
            const float w01 = w2[(size_t)c*512 + 256 + t];
            const float w10 = w2[(size_t)(c+1)*512 + t];
            const float w11 = w2[(size_t)(c+1)*512 + 256 + t];
            #pragma unroll
            for (int r = 0; r < TN; ++r) {
                const float2 hv = *(const float2*)&s_h[r][c];
                acc0[r] += hv.x*w00 + hv.y*w10;
                acc1[r] += hv.x*w01 + hv.y*w11;
            }
        }
        const float bb0 = b2[t], bb1 = b2[256 + t];
        #pragma unroll
        for (int r = 0; r < TN; ++r) {
            outc[(size_t)(n0 + r)*512 + t]       = acc0[r] + bb0;
            outc[(size_t)(n0 + r)*512 + 256 + t] = acc1[r] + bb1;
        }
    }
}

extern "C" void kernel_launch(void* const* d_in, const int* in_sizes, int n_in,
                              void* d_out, int out_size, void* d_ws, size_t ws_size,
                              hipStream_t stream)
{
    const float* feats   = (const float*)d_in[0];
    const int*   nbr1    = (const int*)  d_in[1];
    const int*   nbr2    = (const int*)  d_in[2];
    const float* w_rgb   = (const float*)d_in[3];
    const float* b_rgb   = (const float*)d_in[4];
    const float* bn_rgb  = (const float*)d_in[5];
    const float* w_img   = (const float*)d_in[6];
    const float* b_img   = (const float*)d_in[7];
    const float* bn_img  = (const float*)d_in[8];
    const float* w_e1    = (const float*)d_in[9];
    const float* w_e2    = (const float*)d_in[10];
    const float* bn_e1   = (const float*)d_in[11];
    const float* bn_e2   = (const float*)d_in[12];
    const float* w_lab   = (const float*)d_in[13];
    const float* w_unlab = (const float*)d_in[14];
    const float* w_over  = (const float*)d_in[15];
    const float* w_clip1 = (const float*)d_in[16];
    const float* b_clip1 = (const float*)d_in[17];
    const float* bn_clip = (const float*)d_in[18];
    const float* w_clip2 = (const float*)d_in[19];
    const float* b_clip2 = (const float*)d_in[20];

    float* out = (float*)d_out;
    const size_t off_unlab = (size_t)NNODES * 19;
    const size_t off_over  = (size_t)NNODES * 44;
    const size_t off_x     = (size_t)NNODES * 119;
    const size_t off_clip  = (size_t)NNODES * 215;

    // scratch inside the clip-feats output region (dead until clip_kernel, which is last)
    char* scratch = (char*)(out + off_clip);
    unsigned short* x64b  = (unsigned short*)scratch;                        // 65536*64*2  = 8 MB
    unsigned short* x96b  = (unsigned short*)(scratch + (8u << 20));        // 65536*96*2  = 12.6 MB
    unsigned short* wpre1 = (unsigned short*)(scratch + (21u << 20));       // 27*96*128 B = 332 KB
    unsigned short* wpre2 = (unsigned short*)(scratch + (22u << 20));       // 27*96*256 B = 664 KB

    prep_w_kernel<<<(KNBR*96*8*8  + 255) / 256, 256, 0, stream>>>(w_e1, wpre1, 64, 8);
    prep_w_kernel<<<(KNBR*96*16*8 + 255) / 256, 256, 0, stream>>>(w_e2, wpre2, 96, 16);

    stage1_kernel<<<NNODES/4, 256, 0, stream>>>(feats, w_rgb, b_rgb, bn_rgb, w_img, b_img, bn_img, x64b);

    spconv_mfma<64, true ><<<NNODES/128, 256, 0, stream>>>((const char*)x64b, nbr1, (const char*)wpre1,
                                                           bn_e1, nullptr, x96b);
    spconv_mfma<96, false><<<NNODES/128, 256, 0, stream>>>((const char*)x96b, nbr2, (const char*)wpre2,
                                                           bn_e2, out + off_x, nullptr);

    heads_kernel<<<NNODES/32, 256, 0, stream>>>(out + off_x, w_lab, w_unlab, w_over,
                                                out, out + off_unlab, out + off_over);
    clip_kernel<<<NNODES/16, 256, 0, stream>>>(out + off_x, w_clip1, b_clip1, bn_clip,
                                               w_clip2, b_clip2, out + off_clip);
}

// Round 3
// 351.006 us; speedup vs baseline: 6.0064x; 2.0148x over previous
//
#include <hip/hip_runtime.h>
#include <math.h>

#define NNODES 65536
#define KNBR 27
#define EPS_BN 1e-5f
#define LOG_P 4.6151205168412597f

typedef float f32x4 __attribute__((ext_vector_type(4)));
typedef short s16x8 __attribute__((ext_vector_type(8)));   // 8 bf16 in 4 VGPRs

__device__ __forceinline__ unsigned short f2bf(float f) {
    union { float f; unsigned int u; } v; v.f = f;
    unsigned int u = v.u;
    unsigned int r = (u + 0x7fffu + ((u >> 16) & 1u)) >> 16;   // RNE
    return (unsigned short)r;
}

__device__ __forceinline__ void gload16(const void* g, void* l) {
    __builtin_amdgcn_global_load_lds(
        (const __attribute__((address_space(1))) void*)g,
        (__attribute__((address_space(3))) void*)l, 16, 0, 0);
}

// ---------------- W preprocessing for spconv: [k][cin][dout] f32 -> [k][dout][chunk swizzled] bf16 ----------------
__global__ __launch_bounds__(256) void prep_w_kernel(
    const float* __restrict__ W, unsigned short* __restrict__ wpre, int CIN, int NCH)
{
    const int idx = blockIdx.x * 256 + threadIdx.x;
    const int total = KNBR * 96 * NCH * 8;
    if (idx >= total) return;
    const int e  = idx & 7;
    const int t1 = idx >> 3;
    const int ci = t1 % NCH;
    const int t2 = t1 / NCH;
    const int r  = t2 % 96;
    const int k  = t2 / 96;
    const int cc  = ci ^ (r & (NCH - 1));
    const int cin = cc * 8 + e;
    float v = (cin < CIN) ? W[((size_t)k * CIN + cin) * 96 + r] : 0.f;
    wpre[idx] = f2bf(v);
}

// ---------------- stage 1: entropy gate + rgb/img matvec -> x64 (bf16) ----------------
__global__ __launch_bounds__(256) void stage1_kernel(
    const float* __restrict__ feats,
    const float* __restrict__ w_rgb, const float* __restrict__ b_rgb, const float* __restrict__ bn_rgb,
    const float* __restrict__ w_img, const float* __restrict__ b_img, const float* __restrict__ bn_img,
    unsigned short* __restrict__ x64b)
{
    __shared__ float s_f[4][106];
    const int wid  = threadIdx.x >> 6;
    const int lane = threadIdx.x & 63;
    const int n = blockIdx.x * 4 + wid;
    const float* fr = feats + (size_t)n * 105;
    for (int i = lane; i < 105; i += 64) s_f[wid][i] = fr[i];
    __syncthreads();

    float s = 0.f;
    for (int i = lane; i < 101; i += 64) {
        float pv = s_f[wid][4 + i];
        float ps = fmaxf(pv, 1e-12f);
        s += ps * logf(ps);
    }
    #pragma unroll
    for (int off = 32; off > 0; off >>= 1) s += __shfl_xor(s, off, 64);
    const float wgt = 1.0f + s * (1.0f / LOG_P);   // 1 - H/LOG_P

    if (lane < 32) {
        const int j = lane;
        float acc = b_rgb[j];
        #pragma unroll
        for (int c = 0; c < 4; ++c) acc += s_f[wid][c] * w_rgb[c*32 + j];
        float y = bn_rgb[j] * (acc - bn_rgb[64+j]) * rsqrtf(bn_rgb[96+j] + EPS_BN) + bn_rgb[32+j];
        x64b[(size_t)n*64 + j] = f2bf(fmaxf(y, 0.f));
    } else {
        const int j = lane - 32;
        float acc = 0.f;
        for (int c = 0; c < 101; ++c) acc += s_f[wid][4+c] * w_img[c*32 + j];
        acc = acc * wgt + b_img[j];
        float y = bn_img[j] * (acc - bn_img[64+j]) * rsqrtf(bn_img[96+j] + EPS_BN) + bn_img[32+j];
        x64b[(size_t)n*64 + 32 + j] = f2bf(fmaxf(y, 0.f));
    }
}

// ---------------- spconv via MFMA (unchanged, proven) ----------------
template<int CIN, bool OUTBF>
__global__ __launch_bounds__(256, 2) void spconv_mfma(
    const char* __restrict__ xinb,
    const int*  __restrict__ nbr,
    const char* __restrict__ wpre,
    const float* __restrict__ bnp,
    float* __restrict__ outf,
    unsigned short* __restrict__ outb)
{
    constexpr int KT   = CIN / 32;
    constexpr int NCH  = (CIN == 96) ? 16 : 8;
    constexpr int CM   = NCH - 1;
    constexpr int ROWB = NCH * 16;
    constexpr int STG  = (96 * ROWB) / 4096;

    __shared__ int s_nbr[128 * KNBR];
    __shared__ __align__(16) char s_b[2][96 * ROWB];

    const int t   = threadIdx.x;
    const int wid = t >> 6;
    const int l   = t & 63;
    const int l15 = l & 15;
    const int l4  = l >> 4;
    const int n0  = blockIdx.x * 128;

    for (int i = t; i < 128 * KNBR; i += 256) s_nbr[i] = nbr[(size_t)n0 * KNBR + i];

    f32x4 acc[2][6];
    #pragma unroll
    for (int mt = 0; mt < 2; ++mt)
        #pragma unroll
        for (int nt = 0; nt < 6; ++nt) acc[mt][nt] = (f32x4){0.f, 0.f, 0.f, 0.f};

    float sc[6], mb[6], bb[6];
    #pragma unroll
    for (int nt = 0; nt < 6; ++nt) {
        const int d = nt * 16 + l15;
        sc[nt] = bnp[d] * rsqrtf(bnp[288 + d] + EPS_BN);
        mb[nt] = bnp[192 + d];
        bb[nt] = bnp[96 + d];
    }

    s16x8 aA[2][KT], aB[2][KT];

#define STAGE(kk) do {                                                         \
    const char* _src = wpre + (size_t)(kk) * (96 * ROWB);                      \
    char* _dst = &s_b[(kk) & 1][0];                                            \
    _Pragma("unroll")                                                          \
    for (int _i = 0; _i < STG; ++_i)                                           \
        gload16(_src + _i * 4096 + t * 16, _dst + _i * 4096 + (wid << 10));    \
} while (0)

#define PRE(areg, kk) do {                                                     \
    _Pragma("unroll")                                                          \
    for (int _mt = 0; _mt < 2; ++_mt) {                                        \
        const int _nb = s_nbr[(wid * 32 + _mt * 16 + l15) * KNBR + (kk)];      \
        const char* _rp = xinb + (size_t)_nb * (CIN * 2) + (l4 << 4);          \
        _Pragma("unroll")                                                      \
        for (int _kt = 0; _kt < KT; ++_kt)                                     \
            areg[_mt][_kt] = *(const s16x8*)(_rp + _kt * 64);                  \
    }                                                                          \
} while (0)

#define COMP(areg, kk) do {                                                    \
    const char* _bb = &s_b[(kk) & 1][0];                                       \
    _Pragma("unroll")                                                          \
    for (int _kt = 0; _kt < KT; ++_kt) {                                       \
        s16x8 _bf[6];                                                          \
        _Pragma("unroll")                                                      \
        for (int _nt = 0; _nt < 6; ++_nt) {                                    \
            const int _row = _nt * 16 + l15;                                   \
            const int _c   = _kt * 4 + l4;                                     \
            _bf[_nt] = *(const s16x8*)(_bb + _row * ROWB + ((_c ^ (_row & CM)) << 4)); \
        }                                                                      \
        _Pragma("unroll")                                                      \
        for (int _nt = 0; _nt < 6; ++_nt) {                                    \
            acc[0][_nt] = __builtin_amdgcn_mfma_f32_16x16x32_bf16(areg[0][_kt], _bf[_nt], acc[0][_nt], 0, 0, 0); \
            acc[1][_nt] = __builtin_amdgcn_mfma_f32_16x16x32_bf16(areg[1][_kt], _bf[_nt], acc[1][_nt], 0, 0, 0); \
        }                                                                      \
    }                                                                          \
} while (0)

    __syncthreads();
    PRE(aA, 0);
    STAGE(0);
    __syncthreads();

    for (int k = 0; k < 26; k += 2) {
        STAGE(k + 1);
        PRE(aB, k + 1);
        COMP(aA, k);
        __syncthreads();
        STAGE(k + 2);
        PRE(aA, k + 2);
        COMP(aB, k + 1);
        __syncthreads();
    }
    COMP(aA, 26);

#undef STAGE
#undef PRE
#undef COMP

    #pragma unroll
    for (int mt = 0; mt < 2; ++mt)
        #pragma unroll
        for (int nt = 0; nt < 6; ++nt) {
            const int d = nt * 16 + l15;
            #pragma unroll
            for (int q = 0; q < 4; ++q) {
                const int node = n0 + wid * 32 + mt * 16 + l4 * 4 + q;
                float y = sc[nt] * (acc[mt][nt][q] - mb[nt]) + bb[nt];
                y = fmaxf(y, 0.f);
                if (OUTBF) outb[(size_t)node * 96 + d] = f2bf(y);
                else       outf[(size_t)node * 96 + d] = y;
            }
        }
}

// ---------------- fused clip1 + heads + clip2, h kept in LDS ----------------
// 512 thr (8 waves), 128 rows/block, grid 512. Dynamic LDS 128 KiB:
//   region0 [0,64K): phase1 per-kt B (24.5K) / phase2 w2 double-buffer (2x32K)
//   s_h     [64K,128K): h [128 rows][256 cols] bf16, chunk-XOR-swizzled
__global__ __launch_bounds__(512, 2) void fused_clip_heads(
    const float* __restrict__ x,
    const float* __restrict__ w_clip1, const float* __restrict__ b_clip1, const float* __restrict__ bn_clip,
    const float* __restrict__ w_lab, const float* __restrict__ w_unlab, const float* __restrict__ w_over,
    const float* __restrict__ w_clip2, const float* __restrict__ b_clip2,
    float* __restrict__ out_lab, float* __restrict__ out_unlab, float* __restrict__ out_over,
    float* __restrict__ outc)
{
    extern __shared__ __align__(16) char lds[];
    char* reg0 = lds;            // 65536
    char* s_h  = lds + 65536;    // 65536

    const int t   = threadIdx.x;
    const int wid = t >> 6;
    const int l   = t & 63;
    const int l15 = l & 15;
    const int l4  = l >> 4;
    const int wm  = wid >> 2;    // 0..1 (row half)
    const int wn  = wid & 3;     // 0..3 (col group)
    const int r0  = blockIdx.x * 128;

    // ================= phase 1: [x | 384 cols of (w_clip1 | heads)] =================
    f32x4 acc1[4][6];
    #pragma unroll
    for (int mt = 0; mt < 4; ++mt)
        #pragma unroll
        for (int nt = 0; nt < 6; ++nt) acc1[mt][nt] = (f32x4){0.f,0.f,0.f,0.f};

    for (int kt = 0; kt < 3; ++kt) {
        __syncthreads();
        // stage B1 k-slice: [384 cols][4 chunks][8 bf16], pos p2 holds logical chunk kt*4 + (p2^(col&3))
        for (int i = t; i < 384*32; i += 512) {
            const int col = i >> 5, j = i & 31, p2 = j >> 3, e = j & 7;
            const int cin = (kt*4 + (p2 ^ (col & 3)))*8 + e;
            float v;
            if (col < 256)      v = w_clip1[(size_t)cin*256 + col];
            else if (col < 275) v = w_lab[(size_t)cin*19 + (col - 256)];
            else if (col < 300) { int jj = col - 275, hh = jj/5,  p = jj - hh*5;  v = w_unlab[((size_t)hh*96 + cin)*5  + p]; }
            else if (col < 375) { int jj = col - 300, hh = jj/15, p = jj - hh*15; v = w_over [((size_t)hh*96 + cin)*15 + p]; }
            else v = 0.f;
            *(unsigned short*)(reg0 + col*64 + (p2 << 4) + e*2) = f2bf(v);
        }
        __syncthreads();
        // A-frags on the fly from f32 x
        s16x8 af[4];
        #pragma unroll
        for (int mt = 0; mt < 4; ++mt) {
            const int r = r0 + wm*64 + mt*16 + l15;
            const float* bp = x + (size_t)r*96 + kt*32 + l4*8;
            const float4 xa = *(const float4*)bp;
            const float4 xb = *(const float4*)(bp + 4);
            s16x8 v;
            v[0]=(short)f2bf(xa.x); v[1]=(short)f2bf(xa.y); v[2]=(short)f2bf(xa.z); v[3]=(short)f2bf(xa.w);
            v[4]=(short)f2bf(xb.x); v[5]=(short)f2bf(xb.y); v[6]=(short)f2bf(xb.z); v[7]=(short)f2bf(xb.w);
            af[mt] = v;
        }
        s16x8 bf[6];
        #pragma unroll
        for (int nt = 0; nt < 6; ++nt) {
            const int col = wn*96 + nt*16 + l15;
            bf[nt] = *(const s16x8*)(reg0 + col*64 + ((l4 ^ (col & 3)) << 4));
        }
        #pragma unroll
        for (int nt = 0; nt < 6; ++nt)
            #pragma unroll
            for (int mt = 0; mt < 4; ++mt)
                acc1[mt][nt] = __builtin_amdgcn_mfma_f32_16x16x32_bf16(af[mt], bf[nt], acc1[mt][nt], 0, 0, 0);
    }

    // epilogue 1: h -> s_h (swizzled bf16); heads -> global scatter
    #pragma unroll
    for (int nt = 0; nt < 6; ++nt) {
        const int j = wn*96 + nt*16 + l15;
        if (j < 256) {
            const float sc = bn_clip[j] * rsqrtf(bn_clip[768 + j] + EPS_BN);
            const float mb = bn_clip[512 + j];
            const float bb = bn_clip[256 + j];
            const float bias = b_clip1[j];
            const int c = j >> 3, e = j & 7;
            #pragma unroll
            for (int mt = 0; mt < 4; ++mt)
                #pragma unroll
                for (int q = 0; q < 4; ++q) {
                    const int row = wm*64 + mt*16 + l4*4 + q;
                    float y = fmaxf(sc * (acc1[mt][nt][q] + bias - mb) + bb, 0.f);
                    *(unsigned short*)(s_h + row*512 + ((c ^ (row & 31)) << 4) + e*2) = f2bf(y);
                }
        } else if (j < 375) {
            const int jh = j - 256;
            #pragma unroll
            for (int mt = 0; mt < 4; ++mt)
                #pragma unroll
                for (int q = 0; q < 4; ++q) {
                    const int n = r0 + wm*64 + mt*16 + l4*4 + q;
                    const float v = acc1[mt][nt][q];
                    if (jh < 19)      out_lab[(size_t)n*19 + jh] = v;
                    else if (jh < 44) { int jj = jh-19, hh = jj/5,  p = jj-hh*5;  out_unlab[((size_t)hh*NNODES + n)*5  + p] = v; }
                    else              { int jj = jh-44, hh = jj/15, p = jj-hh*15; out_over [((size_t)hh*NNODES + n)*15 + p] = v; }
                }
        }
    }
    __syncthreads();   // s_h complete; reg0 reads done -> safe to restage

    // ================= phase 2: h @ w_clip2 =================
    f32x4 acc2[4][8];
    #pragma unroll
    for (int mt = 0; mt < 4; ++mt)
        #pragma unroll
        for (int nt = 0; nt < 8; ++nt) acc2[mt][nt] = (f32x4){0.f,0.f,0.f,0.f};

#define STAGE2(kt, dst) do {                                                        \
    const float* _ws = w_clip2 + (size_t)(kt)*32*512;                               \
    _Pragma("unroll")                                                               \
    for (int _ii = 0; _ii < 4; ++_ii) {                                             \
        const int _i = _ii*512 + t;                                                 \
        const int _kk2 = _i >> 7;                                                   \
        const int _n0 = (_i & 127) << 2;                                            \
        const float4 _va = *(const float4*)(_ws + (size_t)(_kk2*2    )*512 + _n0);  \
        const float4 _vb = *(const float4*)(_ws + (size_t)(_kk2*2 + 1)*512 + _n0);  \
        const int _c = _kk2 >> 2;                                                   \
        const int _e = (_kk2*2) & 7;                                                \
        _Pragma("unroll")                                                           \
        for (int _d = 0; _d < 4; ++_d) {                                            \
            const int _n = _n0 + _d;                                                \
            const unsigned int _pk = (unsigned int)f2bf(((const float*)&_va)[_d])   \
                                   | ((unsigned int)f2bf(((const float*)&_vb)[_d]) << 16); \
            *(unsigned int*)((dst) + _n*64 + ((_c ^ (_n & 3)) << 4) + _e*2) = _pk;  \
        }                                                                           \
    }                                                                               \
} while (0)

    STAGE2(0, reg0);
    __syncthreads();
    for (int kt = 0; kt < 8; ++kt) {
        if (kt < 7) STAGE2(kt + 1, reg0 + ((kt + 1) & 1)*32768);
        const char* buf = reg0 + (kt & 1)*32768;
        s16x8 a2[4];
        #pragma unroll
        for (int mt = 0; mt < 4; ++mt) {
            const int row = wm*64 + mt*16 + l15;
            a2[mt] = *(const s16x8*)(s_h + row*512 + (((kt*4 + l4) ^ (row & 31)) << 4));
        }
        s16x8 b2[8];
        #pragma unroll
        for (int nt = 0; nt < 8; ++nt) {
            const int col = wn*128 + nt*16 + l15;
            b2[nt] = *(const s16x8*)(buf + col*64 + ((l4 ^ (col & 3)) << 4));
        }
        #pragma unroll
        for (int nt = 0; nt < 8; ++nt)
            #pragma unroll
            for (int mt = 0; mt < 4; ++mt)
                acc2[mt][nt] = __builtin_amdgcn_mfma_f32_16x16x32_bf16(a2[mt], b2[nt], acc2[mt][nt], 0, 0, 0);
        __syncthreads();
    }
#undef STAGE2

    // epilogue 2: + bias, f32 out
    #pragma unroll
    for (int nt = 0; nt < 8; ++nt) {
        const int col = wn*128 + nt*16 + l15;
        const float bb = b_clip2[col];
        #pragma unroll
        for (int mt = 0; mt < 4; ++mt)
            #pragma unroll
            for (int q = 0; q < 4; ++q) {
                const int row = wm*64 + mt*16 + l4*4 + q;
                outc[(size_t)(r0 + row)*512 + col] = acc2[mt][nt][q] + bb;
            }
    }
}

extern "C" void kernel_launch(void* const* d_in, const int* in_sizes, int n_in,
                              void* d_out, int out_size, void* d_ws, size_t ws_size,
                              hipStream_t stream)
{
    const float* feats   = (const float*)d_in[0];
    const int*   nbr1    = (const int*)  d_in[1];
    const int*   nbr2    = (const int*)  d_in[2];
    const float* w_rgb   = (const float*)d_in[3];
    const float* b_rgb   = (const float*)d_in[4];
    const float* bn_rgb  = (const float*)d_in[5];
    const float* w_img   = (const float*)d_in[6];
    const float* b_img   = (const float*)d_in[7];
    const float* bn_img  = (const float*)d_in[8];
    const float* w_e1    = (const float*)d_in[9];
    const float* w_e2    = (const float*)d_in[10];
    const float* bn_e1   = (const float*)d_in[11];
    const float* bn_e2   = (const float*)d_in[12];
    const float* w_lab   = (const float*)d_in[13];
    const float* w_unlab = (const float*)d_in[14];
    const float* w_over  = (const float*)d_in[15];
    const float* w_clip1 = (const float*)d_in[16];
    const float* b_clip1 = (const float*)d_in[17];
    const float* bn_clip = (const float*)d_in[18];
    const float* w_clip2 = (const float*)d_in[19];
    const float* b_clip2 = (const float*)d_in[20];

    float* out = (float*)d_out;
    const size_t off_unlab = (size_t)NNODES * 19;
    const size_t off_over  = (size_t)NNODES * 44;
    const size_t off_x     = (size_t)NNODES * 119;
    const size_t off_clip  = (size_t)NNODES * 215;

    // scratch inside the clip-feats output region — all dead before fused_clip_heads runs
    char* scratch = (char*)(out + off_clip);
    unsigned short* x64b  = (unsigned short*)scratch;                   // 8 MB
    unsigned short* x96b  = (unsigned short*)(scratch + (8u << 20));    // 12.6 MB
    unsigned short* wpre1 = (unsigned short*)(scratch + (21u << 20));   // 332 KB
    unsigned short* wpre2 = (unsigned short*)(scratch + (22u << 20));   // 664 KB

    prep_w_kernel<<<(KNBR*96*8*8  + 255) / 256, 256, 0, stream>>>(w_e1, wpre1, 64, 8);
    prep_w_kernel<<<(KNBR*96*16*8 + 255) / 256, 256, 0, stream>>>(w_e2, wpre2, 96, 16);

    stage1_kernel<<<NNODES/4, 256, 0, stream>>>(feats, w_rgb, b_rgb, bn_rgb, w_img, b_img, bn_img, x64b);

    spconv_mfma<64, true ><<<NNODES/128, 256, 0, stream>>>((const char*)x64b, nbr1, (const char*)wpre1,
                                                           bn_e1, nullptr, x96b);
    spconv_mfma<96, false><<<NNODES/128, 256, 0, stream>>>((const char*)x96b, nbr2, (const char*)wpre2,
                                                           bn_e2, out + off_x, nullptr);

    fused_clip_heads<<<NNODES/128, 512, 131072, stream>>>(
        out + off_x, w_clip1, b_clip1, bn_clip, w_lab, w_unlab, w_over, w_clip2, b_clip2,
        out, out + off_unlab, out + off_over, out + off_clip);
}

// Round 4
// 252.371 us; speedup vs baseline: 8.3539x; 1.3908x over previous
//
#include <hip/hip_runtime.h>
#include <math.h>

#define NNODES 65536
#define KNBR 27
#define EPS_BN 1e-5f
#define LOG_P 4.6151205168412597f

typedef float f32x4 __attribute__((ext_vector_type(4)));
typedef short s16x8 __attribute__((ext_vector_type(8)));   // 8 bf16 in 4 VGPRs

__device__ __forceinline__ unsigned short f2bf(float f) {
    union { float f; unsigned int u; } v; v.f = f;
    unsigned int u = v.u;
    unsigned int r = (u + 0x7fffu + ((u >> 16) & 1u)) >> 16;   // RNE
    return (unsigned short)r;
}

__device__ __forceinline__ void gload16(const void* g, void* l) {
    __builtin_amdgcn_global_load_lds(
        (const __attribute__((address_space(1))) void*)g,
        (__attribute__((address_space(3))) void*)l, 16, 0, 0);
}

// ---------------- W preprocessing for spconv: [k][cin][dout] f32 -> [k][dout][chunk swizzled] bf16 ----------------
__global__ __launch_bounds__(256) void prep_w_kernel(
    const float* __restrict__ W, unsigned short* __restrict__ wpre, int CIN, int NCH)
{
    const int idx = blockIdx.x * 256 + threadIdx.x;
    const int total = KNBR * 96 * NCH * 8;
    if (idx >= total) return;
    const int e  = idx & 7;
    const int t1 = idx >> 3;
    const int ci = t1 % NCH;
    const int t2 = t1 / NCH;
    const int r  = t2 % 96;
    const int k  = t2 / 96;
    const int cc  = ci ^ (r & (NCH - 1));
    const int cin = cc * 8 + e;
    float v = (cin < CIN) ? W[((size_t)k * CIN + cin) * 96 + r] : 0.f;
    wpre[idx] = f2bf(v);
}

// ---------------- prep for fused phase-1 B image: [3 kt][384 col][4 pos][8 e] bf16 ----------------
// position p2 holds logical chunk p2 ^ ((col>>2)&3); cin = (kt*4 + chunk)*8 + e
__global__ __launch_bounds__(256) void prep_wc1h_kernel(
    const float* __restrict__ w_clip1, const float* __restrict__ w_lab,
    const float* __restrict__ w_unlab, const float* __restrict__ w_over,
    unsigned short* __restrict__ out)
{
    const int idx = blockIdx.x * 256 + threadIdx.x;
    if (idx >= 3 * 384 * 32) return;
    const int e   = idx & 7;
    const int p2  = (idx >> 3) & 3;
    const int col = (idx >> 5) % 384;
    const int kt  = (idx >> 5) / 384;
    const int cin = (kt * 4 + (p2 ^ ((col >> 2) & 3))) * 8 + e;
    float v;
    if (col < 256)      v = w_clip1[(size_t)cin * 256 + col];
    else if (col < 275) v = w_lab[(size_t)cin * 19 + (col - 256)];
    else if (col < 300) { int jj = col - 275, hh = jj / 5,  p = jj - hh * 5;  v = w_unlab[((size_t)hh * 96 + cin) * 5  + p]; }
    else if (col < 375) { int jj = col - 300, hh = jj / 15, p = jj - hh * 15; v = w_over [((size_t)hh * 96 + cin) * 15 + p]; }
    else v = 0.f;
    out[idx] = f2bf(v);
}

// ---------------- prep for fused phase-2 B image: [8 kt][512 col][4 pos][8 e] bf16 ----------------
__global__ __launch_bounds__(256) void prep_wc2_kernel(
    const float* __restrict__ w_clip2, unsigned short* __restrict__ out)
{
    const int idx = blockIdx.x * 256 + threadIdx.x;   // 131072 total
    const int e   = idx & 7;
    const int p2  = (idx >> 3) & 3;
    const int col = (idx >> 5) & 511;
    const int kt  = idx >> 14;
    const int cin = (kt * 4 + (p2 ^ ((col >> 2) & 3))) * 8 + e;
    out[idx] = f2bf(w_clip2[(size_t)cin * 512 + col]);
}

// ---------------- stage 1: entropy gate + rgb/img matvec -> x64 (bf16) ----------------
__global__ __launch_bounds__(256) void stage1_kernel(
    const float* __restrict__ feats,
    const float* __restrict__ w_rgb, const float* __restrict__ b_rgb, const float* __restrict__ bn_rgb,
    const float* __restrict__ w_img, const float* __restrict__ b_img, const float* __restrict__ bn_img,
    unsigned short* __restrict__ x64b)
{
    __shared__ float s_f[4][106];
    const int wid  = threadIdx.x >> 6;
    const int lane = threadIdx.x & 63;
    const int n = blockIdx.x * 4 + wid;
    const float* fr = feats + (size_t)n * 105;
    for (int i = lane; i < 105; i += 64) s_f[wid][i] = fr[i];
    __syncthreads();

    float s = 0.f;
    for (int i = lane; i < 101; i += 64) {
        float pv = s_f[wid][4 + i];
        float ps = fmaxf(pv, 1e-12f);
        s += ps * logf(ps);
    }
    #pragma unroll
    for (int off = 32; off > 0; off >>= 1) s += __shfl_xor(s, off, 64);
    const float wgt = 1.0f + s * (1.0f / LOG_P);

    if (lane < 32) {
        const int j = lane;
        float acc = b_rgb[j];
        #pragma unroll
        for (int c = 0; c < 4; ++c) acc += s_f[wid][c] * w_rgb[c*32 + j];
        float y = bn_rgb[j] * (acc - bn_rgb[64+j]) * rsqrtf(bn_rgb[96+j] + EPS_BN) + bn_rgb[32+j];
        x64b[(size_t)n*64 + j] = f2bf(fmaxf(y, 0.f));
    } else {
        const int j = lane - 32;
        float acc = 0.f;
        for (int c = 0; c < 101; ++c) acc += s_f[wid][4+c] * w_img[c*32 + j];
        acc = acc * wgt + b_img[j];
        float y = bn_img[j] * (acc - bn_img[64+j]) * rsqrtf(bn_img[96+j] + EPS_BN) + bn_img[32+j];
        x64b[(size_t)n*64 + 32 + j] = f2bf(fmaxf(y, 0.f));
    }
}

// ---------------- spconv via MFMA, 3-deep A-gather prefetch ----------------
template<int CIN, bool OUTBF>
__global__ __launch_bounds__(256, 2) void spconv_mfma(
    const char* __restrict__ xinb,
    const int*  __restrict__ nbr,
    const char* __restrict__ wpre,
    const float* __restrict__ bnp,
    float* __restrict__ outf,
    unsigned short* __restrict__ outb)
{
    constexpr int KT   = CIN / 32;
    constexpr int NCH  = (CIN == 96) ? 16 : 8;
    constexpr int CM   = NCH - 1;
    constexpr int ROWB = NCH * 16;
    constexpr int STG  = (96 * ROWB) / 4096;

    __shared__ int s_nbr[128 * KNBR];
    __shared__ __align__(16) char s_b[2][96 * ROWB];

    const int t   = threadIdx.x;
    const int wid = t >> 6;
    const int l   = t & 63;
    const int l15 = l & 15;
    const int l4  = l >> 4;
    const int n0  = blockIdx.x * 128;

    for (int i = t; i < 128 * KNBR; i += 256) s_nbr[i] = nbr[(size_t)n0 * KNBR + i];

    f32x4 acc[2][6];
    #pragma unroll
    for (int mt = 0; mt < 2; ++mt)
        #pragma unroll
        for (int nt = 0; nt < 6; ++nt) acc[mt][nt] = (f32x4){0.f, 0.f, 0.f, 0.f};

    float sc[6], mb[6], bb[6];
    #pragma unroll
    for (int nt = 0; nt < 6; ++nt) {
        const int d = nt * 16 + l15;
        sc[nt] = bnp[d] * rsqrtf(bnp[288 + d] + EPS_BN);
        mb[nt] = bnp[192 + d];
        bb[nt] = bnp[96 + d];
    }

    s16x8 a0[2][KT], a1[2][KT], a2r[2][KT];

#define STAGE(kk) do {                                                         \
    const char* _src = wpre + (size_t)(kk) * (96 * ROWB);                      \
    char* _dst = &s_b[(kk) & 1][0];                                            \
    _Pragma("unroll")                                                          \
    for (int _i = 0; _i < STG; ++_i)                                           \
        gload16(_src + _i * 4096 + t * 16, _dst + _i * 4096 + (wid << 10));    \
} while (0)

#define PRE(areg, kk) do {                                                     \
    _Pragma("unroll")                                                          \
    for (int _mt = 0; _mt < 2; ++_mt) {                                        \
        const int _nb = s_nbr[(wid * 32 + _mt * 16 + l15) * KNBR + (kk)];      \
        const char* _rp = xinb + (size_t)_nb * (CIN * 2) + (l4 << 4);          \
        _Pragma("unroll")                                                      \
        for (int _kt = 0; _kt < KT; ++_kt)                                     \
            areg[_mt][_kt] = *(const s16x8*)(_rp + _kt * 64);                  \
    }                                                                          \
} while (0)

#define COMP(areg, kk) do {                                                    \
    const char* _bb = &s_b[(kk) & 1][0];                                       \
    _Pragma("unroll")                                                          \
    for (int _kt = 0; _kt < KT; ++_kt) {                                       \
        s16x8 _bf[6];                                                          \
        _Pragma("unroll")                                                      \
        for (int _nt = 0; _nt < 6; ++_nt) {                                    \
            const int _row = _nt * 16 + l15;                                   \
            const int _c   = _kt * 4 + l4;                                     \
            _bf[_nt] = *(const s16x8*)(_bb + _row * ROWB + ((_c ^ (_row & CM)) << 4)); \
        }                                                                      \
        _Pragma("unroll")                                                      \
        for (int _nt = 0; _nt < 6; ++_nt) {                                    \
            acc[0][_nt] = __builtin_amdgcn_mfma_f32_16x16x32_bf16(areg[0][_kt], _bf[_nt], acc[0][_nt], 0, 0, 0); \
            acc[1][_nt] = __builtin_amdgcn_mfma_f32_16x16x32_bf16(areg[1][_kt], _bf[_nt], acc[1][_nt], 0, 0, 0); \
        }                                                                      \
    }                                                                          \
} while (0)

    __syncthreads();                 // s_nbr ready
    PRE(a0, 0);
    PRE(a1, 1);
    STAGE(0);
    __syncthreads();

    for (int k = 0; k < 27; k += 3) {
        STAGE(k + 1);
        PRE(a2r, k + 2);
        COMP(a0, k);
        __syncthreads();
        STAGE(k + 2);
        if (k + 3 < 27) PRE(a0, k + 3);
        COMP(a1, k + 1);
        __syncthreads();
        if (k + 3 < 27) STAGE(k + 3);
        if (k + 4 < 27) PRE(a1, k + 4);
        COMP(a2r, k + 2);
        __syncthreads();
    }

#undef STAGE
#undef PRE
#undef COMP

    #pragma unroll
    for (int mt = 0; mt < 2; ++mt)
        #pragma unroll
        for (int nt = 0; nt < 6; ++nt) {
            const int d = nt * 16 + l15;
            #pragma unroll
            for (int q = 0; q < 4; ++q) {
                const int node = n0 + wid * 32 + mt * 16 + l4 * 4 + q;
                float y = sc[nt] * (acc[mt][nt][q] - mb[nt]) + bb[nt];
                y = fmaxf(y, 0.f);
                if (OUTBF) outb[(size_t)node * 96 + d] = f2bf(y);
                else       outf[(size_t)node * 96 + d] = y;
            }
        }
}

// ---------------- fused clip1 + heads + clip2 ----------------
// 512 thr (8 waves), 128 rows/block. Dynamic LDS 128 KiB:
//   reg0 [0,64K): phase1 B dbuf (2x24.5K in 2x32K slots) / phase2 w2 dbuf (2x32K)
//   s_h  [64K,128K): h [128 rows][32 chunk-pos][8 e] bf16, pos = c ^ (row&31)
__global__ __launch_bounds__(512, 2) void fused_clip_heads(
    const float* __restrict__ x,
    const char* __restrict__ wc1h,          // [3][384][4][8] bf16 image
    const char* __restrict__ wc2,           // [8][512][4][8] bf16 image
    const float* __restrict__ b_clip1, const float* __restrict__ bn_clip,
    const float* __restrict__ b_clip2,
    float* __restrict__ out_lab, float* __restrict__ out_unlab, float* __restrict__ out_over,
    float* __restrict__ outc)
{
    extern __shared__ __align__(16) char lds[];
    char* reg0 = lds;            // 65536
    char* s_h  = lds + 65536;    // 65536

    const int t   = threadIdx.x;
    const int wid = t >> 6;
    const int l   = t & 63;
    const int l15 = l & 15;
    const int l4  = l >> 4;
    const int wm  = wid >> 2;    // 0..1 (row half)
    const int wn  = wid & 3;     // 0..3 (col group)
    const int r0  = blockIdx.x * 128;

#define STG1(kt) do {                                                          \
    const char* _s = wc1h + (size_t)(kt) * 24576;                              \
    char* _d = reg0 + ((kt) & 1) * 32768;                                      \
    _Pragma("unroll")                                                          \
    for (int _i = 0; _i < 3; ++_i)                                             \
        gload16(_s + _i * 8192 + t * 16, _d + _i * 8192 + (wid << 10));        \
} while (0)

#define STG2(kt) do {                                                          \
    const char* _s = wc2 + (size_t)(kt) * 32768;                               \
    char* _d = reg0 + ((kt) & 1) * 32768;                                      \
    _Pragma("unroll")                                                          \
    for (int _i = 0; _i < 4; ++_i)                                             \
        gload16(_s + _i * 8192 + t * 16, _d + _i * 8192 + (wid << 10));        \
} while (0)

    // ================= phase 1 =================
    STG1(0);

    // A fragments: convert x (f32) -> bf16 frags for all 3 k-tiles up front
    s16x8 af[3][4];
    #pragma unroll
    for (int kt = 0; kt < 3; ++kt)
        #pragma unroll
        for (int mt = 0; mt < 4; ++mt) {
            const int r = r0 + wm*64 + mt*16 + l15;
            const float* bp = x + (size_t)r*96 + kt*32 + l4*8;
            const float4 xa = *(const float4*)bp;
            const float4 xb = *(const float4*)(bp + 4);
            s16x8 v;
            v[0]=(short)f2bf(xa.x); v[1]=(short)f2bf(xa.y); v[2]=(short)f2bf(xa.z); v[3]=(short)f2bf(xa.w);
            v[4]=(short)f2bf(xb.x); v[5]=(short)f2bf(xb.y); v[6]=(short)f2bf(xb.z); v[7]=(short)f2bf(xb.w);
            af[kt][mt] = v;
        }

    f32x4 acc1[4][6];
    #pragma unroll
    for (int mt = 0; mt < 4; ++mt)
        #pragma unroll
        for (int nt = 0; nt < 6; ++nt) acc1[mt][nt] = (f32x4){0.f,0.f,0.f,0.f};

    __syncthreads();   // STG1(0) landed

    for (int kt = 0; kt < 3; ++kt) {
        if (kt < 2) STG1(kt + 1);
        const char* buf = reg0 + (kt & 1) * 32768;
        s16x8 bf[6];
        #pragma unroll
        for (int nt = 0; nt < 6; ++nt) {
            const int col = wn*96 + nt*16 + l15;
            bf[nt] = *(const s16x8*)(buf + col*64 + ((l4 ^ ((col >> 2) & 3)) << 4));
        }
        #pragma unroll
        for (int nt = 0; nt < 6; ++nt)
            #pragma unroll
            for (int mt = 0; mt < 4; ++mt)
                acc1[mt][nt] = __builtin_amdgcn_mfma_f32_16x16x32_bf16(af[kt][mt], bf[nt], acc1[mt][nt], 0, 0, 0);
        __syncthreads();
    }

    // prefetch first w2 tile while epilogue-1 runs
    STG2(0);

    // epilogue 1: h -> s_h (swizzled bf16); heads -> global scatter
    #pragma unroll
    for (int nt = 0; nt < 6; ++nt) {
        const int j = wn*96 + nt*16 + l15;
        if (j < 256) {
            const float sc = bn_clip[j] * rsqrtf(bn_clip[768 + j] + EPS_BN);
            const float mb = bn_clip[512 + j];
            const float bb = bn_clip[256 + j];
            const float bias = b_clip1[j];
            const int c = j >> 3, e = j & 7;
            #pragma unroll
            for (int mt = 0; mt < 4; ++mt)
                #pragma unroll
                for (int q = 0; q < 4; ++q) {
                    const int row = wm*64 + mt*16 + l4*4 + q;
                    float y = fmaxf(sc * (acc1[mt][nt][q] + bias - mb) + bb, 0.f);
                    *(unsigned short*)(s_h + row*512 + ((c ^ (row & 31)) << 4) + e*2) = f2bf(y);
                }
        } else if (j < 375) {
            const int jh = j - 256;
            #pragma unroll
            for (int mt = 0; mt < 4; ++mt)
                #pragma unroll
                for (int q = 0; q < 4; ++q) {
                    const int n = r0 + wm*64 + mt*16 + l4*4 + q;
                    const float v = acc1[mt][nt][q];
                    if (jh < 19)      out_lab[(size_t)n*19 + jh] = v;
                    else if (jh < 44) { int jj = jh-19, hh = jj/5,  p = jj-hh*5;  out_unlab[((size_t)hh*NNODES + n)*5  + p] = v; }
                    else              { int jj = jh-44, hh = jj/15, p = jj-hh*15; out_over [((size_t)hh*NNODES + n)*15 + p] = v; }
                }
        }
    }
    __syncthreads();   // s_h complete + STG2(0) landed

    // ================= phase 2: h @ w_clip2 =================
    f32x4 acc2[4][8];
    #pragma unroll
    for (int mt = 0; mt < 4; ++mt)
        #pragma unroll
        for (int nt = 0; nt < 8; ++nt) acc2[mt][nt] = (f32x4){0.f,0.f,0.f,0.f};

    for (int kt = 0; kt < 8; ++kt) {
        if (kt < 7) STG2(kt + 1);
        const char* buf = reg0 + (kt & 1) * 32768;
        s16x8 a2[4];
        #pragma unroll
        for (int mt = 0; mt < 4; ++mt) {
            const int row = wm*64 + mt*16 + l15;
            a2[mt] = *(const s16x8*)(s_h + row*512 + (((kt*4 + l4) ^ (row & 31)) << 4));
        }
        s16x8 b2[8];
        #pragma unroll
        for (int nt = 0; nt < 8; ++nt) {
            const int col = wn*128 + nt*16 + l15;
            b2[nt] = *(const s16x8*)(buf + col*64 + ((l4 ^ ((col >> 2) & 3)) << 4));
        }
        #pragma unroll
        for (int nt = 0; nt < 8; ++nt)
            #pragma unroll
            for (int mt = 0; mt < 4; ++mt)
                acc2[mt][nt] = __builtin_amdgcn_mfma_f32_16x16x32_bf16(a2[mt], b2[nt], acc2[mt][nt], 0, 0, 0);
        __syncthreads();
    }
#undef STG1
#undef STG2

    // epilogue 2: + bias, f32 out
    #pragma unroll
    for (int nt = 0; nt < 8; ++nt) {
        const int col = wn*128 + nt*16 + l15;
        const float bb = b_clip2[col];
        #pragma unroll
        for (int mt = 0; mt < 4; ++mt)
            #pragma unroll
            for (int q = 0; q < 4; ++q) {
                const int row = wm*64 + mt*16 + l4*4 + q;
                outc[(size_t)(r0 + row)*512 + col] = acc2[mt][nt][q] + bb;
            }
    }
}

extern "C" void kernel_launch(void* const* d_in, const int* in_sizes, int n_in,
                              void* d_out, int out_size, void* d_ws, size_t ws_size,
                              hipStream_t stream)
{
    const float* feats   = (const float*)d_in[0];
    const int*   nbr1    = (const int*)  d_in[1];
    const int*   nbr2    = (const int*)  d_in[2];
    const float* w_rgb   = (const float*)d_in[3];
    const float* b_rgb   = (const float*)d_in[4];
    const float* bn_rgb  = (const float*)d_in[5];
    const float* w_img   = (const float*)d_in[6];
    const float* b_img   = (const float*)d_in[7];
    const float* bn_img  = (const float*)d_in[8];
    const float* w_e1    = (const float*)d_in[9];
    const float* w_e2    = (const float*)d_in[10];
    const float* bn_e1   = (const float*)d_in[11];
    const float* bn_e2   = (const float*)d_in[12];
    const float* w_lab   = (const float*)d_in[13];
    const float* w_unlab = (const float*)d_in[14];
    const float* w_over  = (const float*)d_in[15];
    const float* w_clip1 = (const float*)d_in[16];
    const float* b_clip1 = (const float*)d_in[17];
    const float* bn_clip = (const float*)d_in[18];
    const float* w_clip2 = (const float*)d_in[19];
    const float* b_clip2 = (const float*)d_in[20];

    float* out = (float*)d_out;
    const size_t off_unlab = (size_t)NNODES * 19;
    const size_t off_over  = (size_t)NNODES * 44;
    const size_t off_x     = (size_t)NNODES * 119;
    const size_t off_clip  = (size_t)NNODES * 215;

    // intermediates inside clip-feats output region — only read by kernels that
    // run BEFORE fused_clip_heads (the sole writer of this region)
    char* scratch = (char*)(out + off_clip);
    unsigned short* x64b  = (unsigned short*)scratch;                   // 8 MB
    unsigned short* x96b  = (unsigned short*)(scratch + (8u << 20));    // 12.6 MB
    unsigned short* wpre1 = (unsigned short*)(scratch + (21u << 20));   // 332 KB
    unsigned short* wpre2 = (unsigned short*)(scratch + (22u << 20));   // 664 KB

    // weight images read BY fused_clip_heads live in d_ws (336 KB)
    char* wc1h = (char*)d_ws;               // 73728 B
    char* wc2  = (char*)d_ws + 73728;       // 262144 B

    prep_w_kernel<<<(KNBR*96*8*8  + 255) / 256, 256, 0, stream>>>(w_e1, wpre1, 64, 8);
    prep_w_kernel<<<(KNBR*96*16*8 + 255) / 256, 256, 0, stream>>>(w_e2, wpre2, 96, 16);
    prep_wc1h_kernel<<<(3*384*32 + 255) / 256, 256, 0, stream>>>(w_clip1, w_lab, w_unlab, w_over,
                                                                 (unsigned short*)wc1h);
    prep_wc2_kernel<<<131072 / 256, 256, 0, stream>>>(w_clip2, (unsigned short*)wc2);

    stage1_kernel<<<NNODES/4, 256, 0, stream>>>(feats, w_rgb, b_rgb, bn_rgb, w_img, b_img, bn_img, x64b);

    spconv_mfma<64, true ><<<NNODES/128, 256, 0, stream>>>((const char*)x64b, nbr1, (const char*)wpre1,
                                                           bn_e1, nullptr, x96b);
    spconv_mfma<96, false><<<NNODES/128, 256, 0, stream>>>((const char*)x96b, nbr2, (const char*)wpre2,
                                                           bn_e2, out + off_x, nullptr);

    fused_clip_heads<<<NNODES/128, 512, 131072, stream>>>(
        out + off_x, wc1h, wc2, b_clip1, bn_clip, b_clip2,
        out, out + off_unlab, out + off_over, out + off_clip);
}